// Round 5
// baseline (133.707 us; speedup 1.0000x reference)
//
#include <hip/hip_runtime.h>
#include <hip/hip_bf16.h>
#include <stdint.h>

// Fused causal attention head, MI355X (gfx950). Round 9 probe, resubmit #2.
// (R2 and R4 both died to infra: GPUAcquisitionTimeout / container failed
// twice; source never executed either time.)
// Identical to R8 except proj_kernel is launched 5x (idempotent: rewrites the
// same bytes; output bit-identical). Delta-dur vs R8 = 4 x proj duration,
// resolving which attribution model is true (proj ~7 / ~11 / ~33 us).
// Next round reverts to 1x proj armed with the measured number.

#define EMBED 384
#define HEAD  64
#define NB    4
#define NT    4096
#define NROWS (NB * NT) // 16384
#define NSPLIT 4

#define SCALE_Q 0.18033688011112042f // 0.125 * log2(e), folded into Q

typedef short bf16x8 __attribute__((ext_vector_type(8)));
typedef float f32x4  __attribute__((ext_vector_type(4)));

__device__ __forceinline__ unsigned short bfround(float f) {
    union { float f; unsigned u; } v; v.f = f;
    return (unsigned short)((v.u + 0x8000u) >> 16);
}
__device__ __forceinline__ unsigned packbf(float lo, float hi) {
    union { float f; unsigned u; } a, b; a.f = lo; b.f = hi;
    return ((a.u + 0x8000u) >> 16) | ((b.u + 0x8000u) & 0xFFFF0000u);
}

// gfx950 lane-group swaps. swap32: A_upper32 <-> B_lower32.
// swap16: A rows 1,3 (16-lane rows) <-> B rows 0,2.
__device__ __forceinline__ void pl_swap32(unsigned& a, unsigned& b) {
    asm("v_permlane32_swap_b32 %0, %1" : "+v"(a), "+v"(b));
}
__device__ __forceinline__ void pl_swap16(unsigned& a, unsigned& b) {
    asm("v_permlane16_swap_b32 %0, %1" : "+v"(a), "+v"(b));
}

// ---------------------------------------------------------------------------
__global__ __launch_bounds__(256)
void wprep_kernel(const float* __restrict__ Wq,
                  const float* __restrict__ Wk,
                  const float* __restrict__ Wv,
                  unsigned short* __restrict__ Wt)
{
    int idx = blockIdx.x * 256 + threadIdx.x;
    int k = idx / 192;
    int n = idx - k * 192;
    int sel = n >> 6, nc = n & 63;
    const float* wp = (sel == 0) ? Wq : ((sel == 1) ? Wk : Wv);
    Wt[n * EMBED + k] = bfround(wp[(size_t)k * HEAD + nc]);
}

// ---------------------------------------------------------------------------
// proj v2 (unchanged from R8): block b -> rows [b*64, b*64+64), 192 cols.
// ---------------------------------------------------------------------------
__global__ __launch_bounds__(512)
void proj_kernel(const float* __restrict__ x,
                 const unsigned short* __restrict__ Wt,
                 unsigned short* __restrict__ Qo,
                 unsigned short* __restrict__ Ko,
                 unsigned short* __restrict__ Vto)
{
    __shared__ __attribute__((aligned(16))) unsigned short ws[2][192][128]; // 96KB
    __shared__ __attribute__((aligned(16))) unsigned short xs[2][64][128];  // 32KB
    unsigned short (*vbuf)[72] = (unsigned short (*)[72])&xs[1][0][0];

    const int t    = threadIdx.x;   // 0..511
    const int lane = t & 63;
    const int w    = t >> 6;        // 0..7
    const int quad = lane >> 4;
    const int l16  = lane & 15;
    const int wr   = w & 3;         // row group (16 rows)
    const int wc   = w >> 2;        // col group (96 cols)
    const int r0   = blockIdx.x * 64;

    const int xr  = t >> 5, xc4 = t & 31;
    const int xch = xc4 >> 1, xsub = (xc4 & 1) * 4;
    const int wrw = t >> 4, wcc = t & 15;

    f32x4 acc[6];
#pragma unroll
    for (int i = 0; i < 6; ++i) acc[i] = (f32x4){0.f, 0.f, 0.f, 0.f};

    float4 xv[4];
    uint4  wv[6];
#pragma unroll
    for (int i = 0; i < 4; ++i)
        xv[i] = *(const float4*)(x + (size_t)(r0 + xr + 16 * i) * EMBED + xc4 * 4);
#pragma unroll
    for (int i = 0; i < 6; ++i)
        wv[i] = *(const uint4*)(Wt + (size_t)(wrw + 32 * i) * EMBED + wcc * 8);

    int cur = 0;
#pragma unroll
    for (int ph = 0; ph < 3; ++ph) {
#pragma unroll
        for (int i = 0; i < 4; ++i) {
            int row = xr + 16 * i;
            uint2 pw; pw.x = packbf(xv[i].x, xv[i].y); pw.y = packbf(xv[i].z, xv[i].w);
            *(uint2*)&xs[cur][row][((xch ^ (row & 15)) << 3) + xsub] = pw;
        }
#pragma unroll
        for (int i = 0; i < 6; ++i) {
            int row = wrw + 32 * i;
            *(uint4*)&ws[cur][row][(wcc ^ (row & 15)) << 3] = wv[i];
        }
        __syncthreads();

        if (ph < 2) {
            const int k0 = (ph + 1) * 128;
#pragma unroll
            for (int i = 0; i < 4; ++i)
                xv[i] = *(const float4*)(x + (size_t)(r0 + xr + 16 * i) * EMBED + k0 + xc4 * 4);
#pragma unroll
            for (int i = 0; i < 6; ++i)
                wv[i] = *(const uint4*)(Wt + (size_t)(wrw + 32 * i) * EMBED + k0 + wcc * 8);
        }

#pragma unroll
        for (int s = 0; s < 4; ++s) {
            bf16x8 a = *(const bf16x8*)&xs[cur][wr * 16 + l16][((s * 4 + quad) ^ l16) << 3];
#pragma unroll
            for (int ng = 0; ng < 6; ++ng) {
                bf16x8 b = *(const bf16x8*)&ws[cur][wc * 96 + ng * 16 + l16][((s * 4 + quad) ^ l16) << 3];
                acc[ng] = __builtin_amdgcn_mfma_f32_16x16x32_bf16(a, b, acc[ng], 0, 0, 0);
            }
        }
        cur ^= 1;
    }
    __syncthreads();

#pragma unroll
    for (int ng = 0; ng < 6; ++ng) {
        int cg = wc * 96 + ng * 16 + l16;
#pragma unroll
        for (int r = 0; r < 4; ++r) {
            int row = r0 + wr * 16 + quad * 4 + r;
            float vv = acc[ng][r];
            if (cg < 64) {
                Qo[(size_t)row * HEAD + cg] = bfround(vv * SCALE_Q);
            } else if (cg < 128) {
                Ko[(size_t)row * HEAD + (cg - 64)] = bfround(vv);
            } else {
                vbuf[cg - 128][wr * 16 + quad * 4 + r] = bfround(vv);
            }
        }
    }
    __syncthreads();
    {
        const int batch = r0 >> 12;
        const int s0 = r0 & (NT - 1);
        const int d = t >> 3, c = t & 7;
        *(uint4*)(Vto + ((size_t)(batch * HEAD + d)) * NT + s0 + c * 8) =
            *(const uint4*)&vbuf[d][c * 8];
    }
}

// ---------------------------------------------------------------------------
// attn: identical to R7.
// ---------------------------------------------------------------------------
__global__ __launch_bounds__(256, 4)
void attn_kernel(const unsigned short* __restrict__ Qi,
                 const unsigned short* __restrict__ Ki,
                 const unsigned short* __restrict__ Vti,
                 float* __restrict__ opart,
                 float* __restrict__ lpart)
{
    __shared__ __attribute__((aligned(16))) unsigned short Kt[2][64][64];
    __shared__ __attribute__((aligned(16))) unsigned short Vs[2][64][64];

    const int t    = threadIdx.x;
    const int w    = t >> 6;
    const int lane = t & 63;
    const int quad = lane >> 4;
    const int l16  = lane & 15;

    const int u = blockIdx.x;
    const int g = u >> 4;
    const int m = (g < 32) ? (63 - g) : (g - 32);
    const int sp = (u >> 2) & 3;
    const int batch = u & 3;
    const int ntiles = (m >= sp) ? (((m - sp) >> 2) + 1) : 0;
    const int q0 = m * 64 + w * 16;

    const unsigned short* Kbg = Ki  + (size_t)batch * NT * HEAD;
    const unsigned short* Vbg = Vti + (size_t)batch * HEAD * NT;

    bf16x8 bq0, bq1;
    {
        const unsigned short* qp = Qi + (size_t)(batch * NT + q0 + l16) * HEAD + quad * 8;
        bq0 = *(const bf16x8*)(qp);
        bq1 = *(const bf16x8*)(qp + 32);
    }

    f32x4 o[4];
#pragma unroll
    for (int i = 0; i < 4; ++i) o[i] = (f32x4){0.f, 0.f, 0.f, 0.f};
    float rs = 0.f;

    const int srow0 = t >> 3, sc = t & 7;
    const int srow1 = (t + 256) >> 3;
    const int scc0 = sc ^ (srow0 & 7);
    const int scc1 = sc ^ (srow1 & 7);
    const int sw = l16 & 7;

    uint4 kr0, kr1, vr0, vr1;
    if (ntiles > 0) {
        const int kt = sp;
        kr0 = *(const uint4*)(Kbg + (size_t)(kt * 64 + srow0) * HEAD + sc * 8);
        kr1 = *(const uint4*)(Kbg + (size_t)(kt * 64 + srow1) * HEAD + sc * 8);
        vr0 = *(const uint4*)(Vbg + (size_t)srow0 * NT + kt * 64 + sc * 8);
        vr1 = *(const uint4*)(Vbg + (size_t)srow1 * NT + kt * 64 + sc * 8);
    }

    int cur = 0;
    for (int j = 0; j < ntiles; ++j) {
        const int kt = sp + 4 * j;
        *(uint4*)&Kt[cur][srow0][scc0 * 8] = kr0;
        *(uint4*)&Kt[cur][srow1][scc1 * 8] = kr1;
        *(uint4*)&Vs[cur][srow0][scc0 * 8] = vr0;
        *(uint4*)&Vs[cur][srow1][scc1 * 8] = vr1;
        __syncthreads();

        if (j + 1 < ntiles) {
            const int ktn = kt + 4;
            kr0 = *(const uint4*)(Kbg + (size_t)(ktn * 64 + srow0) * HEAD + sc * 8);
            kr1 = *(const uint4*)(Kbg + (size_t)(ktn * 64 + srow1) * HEAD + sc * 8);
            vr0 = *(const uint4*)(Vbg + (size_t)srow0 * NT + ktn * 64 + sc * 8);
            vr1 = *(const uint4*)(Vbg + (size_t)srow1 * NT + ktn * 64 + sc * 8);
        }

        const bool diag = (kt == m);
        uint2 pw[4];
#pragma unroll
        for (int ts = 0; ts < 4; ++ts) {
            bf16x8 ak0 = *(const bf16x8*)&Kt[cur][ts * 16 + l16][(quad ^ sw) * 8];
            bf16x8 ak1 = *(const bf16x8*)&Kt[cur][ts * 16 + l16][((4 + quad) ^ sw) * 8];
            f32x4 z = (f32x4){0.f, 0.f, 0.f, 0.f};
            z = __builtin_amdgcn_mfma_f32_16x16x32_bf16(ak0, bq0, z, 0, 0, 0);
            z = __builtin_amdgcn_mfma_f32_16x16x32_bf16(ak1, bq1, z, 0, 0, 0);
            float p[4];
#pragma unroll
            for (int r = 0; r < 4; ++r) {
                float pv = __builtin_amdgcn_exp2f(z[r]);
                if (diag) {
                    int sg = kt * 64 + ts * 16 + quad * 4 + r;
                    pv = (sg > q0 + l16) ? 0.f : pv;
                }
                p[r] = pv;
            }
            rs += (p[0] + p[1]) + (p[2] + p[3]);
            pw[ts].x = packbf(p[0], p[1]);
            pw[ts].y = packbf(p[2], p[3]);
        }

        unsigned a0 = pw[0].x, c0 = pw[0].y, b0 = pw[1].x, d0 = pw[1].y;
        pl_swap32(a0, b0); pl_swap32(c0, d0);
        pl_swap16(a0, b0); pl_swap16(c0, d0);
        unsigned a1 = pw[2].x, c1 = pw[2].y, b1 = pw[3].x, d1 = pw[3].y;
        pl_swap32(a1, b1); pl_swap32(c1, d1);
        pl_swap16(a1, b1); pl_swap16(c1, d1);
        union { unsigned u[4]; bf16x8 v; } ua0, ua1;
        ua0.u[0] = a0; ua0.u[1] = c0; ua0.u[2] = b0; ua0.u[3] = d0;
        ua1.u[0] = a1; ua1.u[1] = c1; ua1.u[2] = b1; ua1.u[3] = d1;
        const bf16x8 ap0 = ua0.v;
        const bf16x8 ap1 = ua1.v;

#pragma unroll
        for (int nd = 0; nd < 4; ++nd) {
            bf16x8 av0 = *(const bf16x8*)&Vs[cur][nd * 16 + l16][(quad ^ sw) * 8];
            bf16x8 av1 = *(const bf16x8*)&Vs[cur][nd * 16 + l16][((4 + quad) ^ sw) * 8];
            o[nd] = __builtin_amdgcn_mfma_f32_16x16x32_bf16(ap0, av0, o[nd], 0, 0, 0);
            o[nd] = __builtin_amdgcn_mfma_f32_16x16x32_bf16(ap1, av1, o[nd], 0, 0, 0);
        }
        cur ^= 1;
    }

    rs += __shfl_xor(rs, 16, 64);
    rs += __shfl_xor(rs, 32, 64);
    if (quad == 0)
        lpart[(size_t)sp * NROWS + batch * NT + q0 + l16] = rs;
    float* ob = opart + (size_t)sp * NROWS * HEAD;
#pragma unroll
    for (int r = 0; r < 4; ++r) {
        size_t off = (size_t)(batch * NT + q0 + quad * 4 + r) * HEAD;
#pragma unroll
        for (int nd = 0; nd < 4; ++nd)
            ob[off + nd * 16 + l16] = o[nd][r];
    }
}

// ---------------------------------------------------------------------------
// combine: out = sum_sp(o_sp) / sum_sp(l_sp), one float4 per thread.
// ---------------------------------------------------------------------------
__global__ __launch_bounds__(256)
void combine_kernel(const float* __restrict__ opart,
                    const float* __restrict__ lpart,
                    float* __restrict__ out)
{
    int gid = blockIdx.x * 256 + threadIdx.x;   // 0 .. NROWS*16-1
    int row = gid >> 4;
    int d4  = (gid & 15) * 4;
    const size_t st = (size_t)NROWS * HEAD;
    const float* p0 = opart + (size_t)row * HEAD + d4;
    f32x4 a = *(const f32x4*)(p0);
    f32x4 b = *(const f32x4*)(p0 + st);
    f32x4 c = *(const f32x4*)(p0 + 2 * st);
    f32x4 d = *(const f32x4*)(p0 + 3 * st);
    float inv = 1.0f / (lpart[row] + lpart[NROWS + row] +
                        lpart[2 * NROWS + row] + lpart[3 * NROWS + row]);
    f32x4 res = (a + b) + (c + d);
    res[0] *= inv; res[1] *= inv; res[2] *= inv; res[3] *= inv;
    *(f32x4*)(out + (size_t)row * HEAD + d4) = res;
}

extern "C" void kernel_launch(void* const* d_in, const int* in_sizes, int n_in,
                              void* d_out, int out_size, void* d_ws, size_t ws_size,
                              hipStream_t stream)
{
    const float* x  = (const float*)d_in[0];
    const float* Wq = (const float*)d_in[1];
    const float* Wk = (const float*)d_in[2];
    const float* Wv = (const float*)d_in[3];
    float* out = (float*)d_out;

    // ws: Q | K | V^T (bf16, 2MB each) | W^T (144KB) | opart (16MB) | lpart (256KB)
    unsigned short* Qw  = (unsigned short*)d_ws;
    unsigned short* Kw  = Qw + (size_t)NROWS * HEAD;
    unsigned short* Vtw = Kw + (size_t)NROWS * HEAD;
    unsigned short* Wtw = Vtw + (size_t)NROWS * HEAD;
    float* opart = (float*)(Wtw + (size_t)192 * EMBED);
    float* lpart = opart + (size_t)NSPLIT * NROWS * HEAD;

    wprep_kernel<<<(192 * EMBED) / 256, 256, 0, stream>>>(Wq, Wk, Wv, Wtw);
    // PROBE: proj launched 5x (idempotent). Delta-dur vs R8 = 4 x proj time.
    for (int rep = 0; rep < 5; ++rep)
        proj_kernel<<<256, 512, 0, stream>>>(x, Wtw, Qw, Kw, Vtw);
    attn_kernel<<<1024, 256, 0, stream>>>(Qw, Kw, Vtw, opart, lpart);
    combine_kernel<<<NROWS * 16 / 256, 256, 0, stream>>>(opart, lpart, out);
}

// Round 6
// 103.773 us; speedup vs baseline: 1.2885x; 1.2885x over previous
//
#include <hip/hip_runtime.h>
#include <hip/hip_bf16.h>
#include <stdint.h>

// Fused causal attention head, MI355X (gfx950). Round 10.
// R9 probe result: proj = 7.0 us (at floor). attn ~22 us is the remaining
// target; it is latency-bound at 16 waves/CU. attn v3: same 1024-block grid
// and split-K=4 mapping, but 512-thr blocks (8 waves) -> 32 waves/CU (the
// occupancy cap). Each wave now owns 16 q-rows x 32 s-cols (s-half split):
// per tile 2 QK MFMA + 1 in-reg P-transform + 4 PV MFMA; the two s-half
// accumulators merge once per block via LDS at the end. packbf -> single
// v_cvt_pk_bf16_f32. Work/LDS/partial traffic conserved; only latency
// hiding doubles. proj reverted to 1x launch. wprep/proj/combine identical.

#define EMBED 384
#define HEAD  64
#define NB    4
#define NT    4096
#define NROWS (NB * NT) // 16384
#define NSPLIT 4

#define SCALE_Q 0.18033688011112042f // 0.125 * log2(e), folded into Q

typedef short bf16x8 __attribute__((ext_vector_type(8)));
typedef float f32x4  __attribute__((ext_vector_type(4)));

__device__ __forceinline__ unsigned short bfround(float f) {
    union { float f; unsigned u; } v; v.f = f;
    return (unsigned short)((v.u + 0x8000u) >> 16);
}
__device__ __forceinline__ unsigned packbf(float lo, float hi) {
    union { float f; unsigned u; } a, b; a.f = lo; b.f = hi;
    return ((a.u + 0x8000u) >> 16) | ((b.u + 0x8000u) & 0xFFFF0000u);
}
__device__ __forceinline__ unsigned cvtpk(float lo, float hi) {
    unsigned r;
    asm("v_cvt_pk_bf16_f32 %0, %1, %2" : "=v"(r) : "v"(lo), "v"(hi));
    return r;
}

// gfx950 lane-group swaps. swap32: A_upper32 <-> B_lower32.
// swap16: A rows 1,3 (16-lane rows) <-> B rows 0,2.
__device__ __forceinline__ void pl_swap32(unsigned& a, unsigned& b) {
    asm("v_permlane32_swap_b32 %0, %1" : "+v"(a), "+v"(b));
}
__device__ __forceinline__ void pl_swap16(unsigned& a, unsigned& b) {
    asm("v_permlane16_swap_b32 %0, %1" : "+v"(a), "+v"(b));
}

// ---------------------------------------------------------------------------
__global__ __launch_bounds__(256)
void wprep_kernel(const float* __restrict__ Wq,
                  const float* __restrict__ Wk,
                  const float* __restrict__ Wv,
                  unsigned short* __restrict__ Wt)
{
    int idx = blockIdx.x * 256 + threadIdx.x;
    int k = idx / 192;
    int n = idx - k * 192;
    int sel = n >> 6, nc = n & 63;
    const float* wp = (sel == 0) ? Wq : ((sel == 1) ? Wk : Wv);
    Wt[n * EMBED + k] = bfround(wp[(size_t)k * HEAD + nc]);
}

// ---------------------------------------------------------------------------
// proj v2 (unchanged from R8, measured 7.0 us ~ at HBM floor).
// ---------------------------------------------------------------------------
__global__ __launch_bounds__(512)
void proj_kernel(const float* __restrict__ x,
                 const unsigned short* __restrict__ Wt,
                 unsigned short* __restrict__ Qo,
                 unsigned short* __restrict__ Ko,
                 unsigned short* __restrict__ Vto)
{
    __shared__ __attribute__((aligned(16))) unsigned short ws[2][192][128]; // 96KB
    __shared__ __attribute__((aligned(16))) unsigned short xs[2][64][128];  // 32KB
    unsigned short (*vbuf)[72] = (unsigned short (*)[72])&xs[1][0][0];

    const int t    = threadIdx.x;   // 0..511
    const int lane = t & 63;
    const int w    = t >> 6;        // 0..7
    const int quad = lane >> 4;
    const int l16  = lane & 15;
    const int wr   = w & 3;         // row group (16 rows)
    const int wc   = w >> 2;        // col group (96 cols)
    const int r0   = blockIdx.x * 64;

    const int xr  = t >> 5, xc4 = t & 31;
    const int xch = xc4 >> 1, xsub = (xc4 & 1) * 4;
    const int wrw = t >> 4, wcc = t & 15;

    f32x4 acc[6];
#pragma unroll
    for (int i = 0; i < 6; ++i) acc[i] = (f32x4){0.f, 0.f, 0.f, 0.f};

    float4 xv[4];
    uint4  wv[6];
#pragma unroll
    for (int i = 0; i < 4; ++i)
        xv[i] = *(const float4*)(x + (size_t)(r0 + xr + 16 * i) * EMBED + xc4 * 4);
#pragma unroll
    for (int i = 0; i < 6; ++i)
        wv[i] = *(const uint4*)(Wt + (size_t)(wrw + 32 * i) * EMBED + wcc * 8);

    int cur = 0;
#pragma unroll
    for (int ph = 0; ph < 3; ++ph) {
#pragma unroll
        for (int i = 0; i < 4; ++i) {
            int row = xr + 16 * i;
            uint2 pw; pw.x = packbf(xv[i].x, xv[i].y); pw.y = packbf(xv[i].z, xv[i].w);
            *(uint2*)&xs[cur][row][((xch ^ (row & 15)) << 3) + xsub] = pw;
        }
#pragma unroll
        for (int i = 0; i < 6; ++i) {
            int row = wrw + 32 * i;
            *(uint4*)&ws[cur][row][(wcc ^ (row & 15)) << 3] = wv[i];
        }
        __syncthreads();

        if (ph < 2) {
            const int k0 = (ph + 1) * 128;
#pragma unroll
            for (int i = 0; i < 4; ++i)
                xv[i] = *(const float4*)(x + (size_t)(r0 + xr + 16 * i) * EMBED + k0 + xc4 * 4);
#pragma unroll
            for (int i = 0; i < 6; ++i)
                wv[i] = *(const uint4*)(Wt + (size_t)(wrw + 32 * i) * EMBED + k0 + wcc * 8);
        }

#pragma unroll
        for (int s = 0; s < 4; ++s) {
            bf16x8 a = *(const bf16x8*)&xs[cur][wr * 16 + l16][((s * 4 + quad) ^ l16) << 3];
#pragma unroll
            for (int ng = 0; ng < 6; ++ng) {
                bf16x8 b = *(const bf16x8*)&ws[cur][wc * 96 + ng * 16 + l16][((s * 4 + quad) ^ l16) << 3];
                acc[ng] = __builtin_amdgcn_mfma_f32_16x16x32_bf16(a, b, acc[ng], 0, 0, 0);
            }
        }
        cur ^= 1;
    }
    __syncthreads();

#pragma unroll
    for (int ng = 0; ng < 6; ++ng) {
        int cg = wc * 96 + ng * 16 + l16;
#pragma unroll
        for (int r = 0; r < 4; ++r) {
            int row = r0 + wr * 16 + quad * 4 + r;
            float vv = acc[ng][r];
            if (cg < 64) {
                Qo[(size_t)row * HEAD + cg] = bfround(vv * SCALE_Q);
            } else if (cg < 128) {
                Ko[(size_t)row * HEAD + (cg - 64)] = bfround(vv);
            } else {
                vbuf[cg - 128][wr * 16 + quad * 4 + r] = bfround(vv);
            }
        }
    }
    __syncthreads();
    {
        const int batch = r0 >> 12;
        const int s0 = r0 & (NT - 1);
        const int d = t >> 3, c = t & 7;
        *(uint4*)(Vto + ((size_t)(batch * HEAD + d)) * NT + s0 + c * 8) =
            *(const uint4*)&vbuf[d][c * 8];
    }
}

// ---------------------------------------------------------------------------
// attn v3: 1024 blocks x 512 thr (4 blocks/CU = 32 waves/CU, the cap).
// Same mapping as R7: g=u>>4, m = g<32 ? 63-g : g-32, sp=(u>>2)&3, batch=u&3,
// kt = sp + 4j <= m. Wave w: qg=w>>1 (16 q-rows at q0=m*64+qg*16), sh=w&1
// (s-half, 32 s-cols). Per tile per wave: 2 QK MFMA, 1 in-reg P-transform
// (cvt_pk + permlane swaps), 4 PV MFMA. Double-buffered K/V LDS, one barrier
// per tile (same proof as R7). s-half partials (o, rs) merged once per block
// through the retired LDS buffers; sh==0 waves write opart/lpart.
// ---------------------------------------------------------------------------
__global__ __launch_bounds__(512, 8)
void attn_kernel(const unsigned short* __restrict__ Qi,
                 const unsigned short* __restrict__ Ki,
                 const unsigned short* __restrict__ Vti,
                 float* __restrict__ opart,
                 float* __restrict__ lpart)
{
    __shared__ __attribute__((aligned(16))) unsigned short Kt[2][64][64];
    __shared__ __attribute__((aligned(16))) unsigned short Vs[2][64][64];

    const int t    = threadIdx.x;   // 0..511
    const int w    = t >> 6;        // 0..7
    const int lane = t & 63;
    const int quad = lane >> 4;
    const int l16  = lane & 15;
    const int qg   = w >> 1;        // q-group: 16 rows
    const int sh   = w & 1;         // s-half: 32 cols

    const int u = blockIdx.x;
    const int g = u >> 4;
    const int m = (g < 32) ? (63 - g) : (g - 32);
    const int sp = (u >> 2) & 3;
    const int batch = u & 3;
    const int ntiles = (m >= sp) ? (((m - sp) >> 2) + 1) : 0;
    const int q0 = m * 64 + qg * 16;

    const unsigned short* Kbg = Ki  + (size_t)batch * NT * HEAD;
    const unsigned short* Vbg = Vti + (size_t)batch * HEAD * NT;

    // Q B-frags (one-time; Q carries 0.125*log2e)
    bf16x8 bq0, bq1;
    {
        const unsigned short* qp = Qi + (size_t)(batch * NT + q0 + l16) * HEAD + quad * 8;
        bq0 = *(const bf16x8*)(qp);
        bq1 = *(const bf16x8*)(qp + 32);
    }

    f32x4 o[4];
#pragma unroll
    for (int i = 0; i < 4; ++i) o[i] = (f32x4){0.f, 0.f, 0.f, 0.f};
    float rs = 0.f;

    // staging: 512 threads, one 16B chunk each of K and V per tile
    const int srow = t >> 3, sc = t & 7;
    const int scc  = sc ^ (srow & 7);      // swizzled chunk
    const int sw   = l16 & 7;              // row-swizzle key for frag reads

    uint4 kr, vr;
    if (ntiles > 0) {
        kr = *(const uint4*)(Kbg + (size_t)(sp * 64 + srow) * HEAD + sc * 8);
        vr = *(const uint4*)(Vbg + (size_t)srow * NT + sp * 64 + sc * 8);
    }

    int cur = 0;
    for (int j = 0; j < ntiles; ++j) {
        const int kt = sp + 4 * j;
        // commit staged regs (safe: buf last read at j-2, barrier at j-1)
        *(uint4*)&Kt[cur][srow][scc * 8] = kr;
        *(uint4*)&Vs[cur][srow][scc * 8] = vr;
        __syncthreads(); // tile visible; j-1 reads complete

        // prefetch next tile AFTER the barrier; hides under this tile's compute
        if (j + 1 < ntiles) {
            const int ktn = kt + 4;
            kr = *(const uint4*)(Kbg + (size_t)(ktn * 64 + srow) * HEAD + sc * 8);
            vr = *(const uint4*)(Vbg + (size_t)srow * NT + ktn * 64 + sc * 8);
        }

        const bool diag = (kt == m);
        uint2 pw[2];
#pragma unroll
        for (int tsl = 0; tsl < 2; ++tsl) {
            const int ts = sh * 2 + tsl;
            bf16x8 ak0 = *(const bf16x8*)&Kt[cur][ts * 16 + l16][(quad ^ sw) * 8];
            bf16x8 ak1 = *(const bf16x8*)&Kt[cur][ts * 16 + l16][((4 + quad) ^ sw) * 8];
            f32x4 z = (f32x4){0.f, 0.f, 0.f, 0.f};
            z = __builtin_amdgcn_mfma_f32_16x16x32_bf16(ak0, bq0, z, 0, 0, 0);
            z = __builtin_amdgcn_mfma_f32_16x16x32_bf16(ak1, bq1, z, 0, 0, 0);
            // z[r] = S^T[s = kt*64+ts*16+quad*4+r][q = q0+l16], exp2 domain
            float p[4];
#pragma unroll
            for (int r = 0; r < 4; ++r) {
                float pv = __builtin_amdgcn_exp2f(z[r]);
                if (diag) {
                    int sg = kt * 64 + ts * 16 + quad * 4 + r;
                    pv = (sg > q0 + l16) ? 0.f : pv;
                }
                p[r] = pv;
            }
            rs += (p[0] + p[1]) + (p[2] + p[3]);
            pw[tsl].x = cvtpk(p[0], p[1]);
            pw[tsl].y = cvtpk(p[2], p[3]);
        }

        // In-register C->A transform for this wave's 32-s half:
        // d[a][c] covers s = 32*sh + 16a + 4*quad + 2c; after swap32+swap16,
        // f0..f3 = A-frag dwords: P[q=l16][s = 32*sh + quad*8 + 0..7].
        unsigned a0 = pw[0].x, c0 = pw[0].y, b0 = pw[1].x, d0 = pw[1].y;
        pl_swap32(a0, b0); pl_swap32(c0, d0);
        pl_swap16(a0, b0); pl_swap16(c0, d0);
        union { unsigned uu[4]; bf16x8 v; } ua;
        ua.uu[0] = a0; ua.uu[1] = c0; ua.uu[2] = b0; ua.uu[3] = d0;
        const bf16x8 ap = ua.v;

        // PV over this s-half: o[nd] += P[q][s-half] x V^T[d][s-half]
#pragma unroll
        for (int nd = 0; nd < 4; ++nd) {
            bf16x8 av = *(const bf16x8*)&Vs[cur][nd * 16 + l16][((4 * sh + quad) ^ sw) * 8];
            o[nd] = __builtin_amdgcn_mfma_f32_16x16x32_bf16(ap, av, o[nd], 0, 0, 0);
        }
        cur ^= 1;
    }

    // rs: butterfly across quads -> every lane holds its s-half sum for q0+l16
    rs += __shfl_xor(rs, 16, 64);
    rs += __shfl_xor(rs, 32, 64);

    // merge s-halves through the retired LDS buffers (once per block)
    __syncthreads(); // all tile reads done; Kt/Vs reusable as scratch
    float* osc = (float*)&Kt[0][0][0]; // 16 KB: [(qg*16 + qsub)*64 + d]
    float* rsc = (float*)&Vs[0][0][0]; // 64 floats: [qg*16 + l16]
    if (sh == 1) {
#pragma unroll
        for (int nd = 0; nd < 4; ++nd)
#pragma unroll
            for (int r = 0; r < 4; ++r)
                osc[(qg * 16 + quad * 4 + r) * 64 + nd * 16 + l16] = o[nd][r];
        if (quad == 0) rsc[qg * 16 + l16] = rs;
    }
    __syncthreads();
    if (sh == 0) {
        rs += rsc[qg * 16 + l16];
        if (quad == 0)
            lpart[(size_t)sp * NROWS + batch * NT + q0 + l16] = rs;
        float* ob = opart + (size_t)sp * NROWS * HEAD;
#pragma unroll
        for (int r = 0; r < 4; ++r) {
            size_t off = (size_t)(batch * NT + q0 + quad * 4 + r) * HEAD;
#pragma unroll
            for (int nd = 0; nd < 4; ++nd)
                ob[off + nd * 16 + l16] =
                    o[nd][r] + osc[(qg * 16 + quad * 4 + r) * 64 + nd * 16 + l16];
        }
    }
}

// ---------------------------------------------------------------------------
// combine: out = sum_sp(o_sp) / sum_sp(l_sp), one float4 per thread.
// ---------------------------------------------------------------------------
__global__ __launch_bounds__(256)
void combine_kernel(const float* __restrict__ opart,
                    const float* __restrict__ lpart,
                    float* __restrict__ out)
{
    int gid = blockIdx.x * 256 + threadIdx.x;   // 0 .. NROWS*16-1
    int row = gid >> 4;
    int d4  = (gid & 15) * 4;
    const size_t st = (size_t)NROWS * HEAD;
    const float* p0 = opart + (size_t)row * HEAD + d4;
    f32x4 a = *(const f32x4*)(p0);
    f32x4 b = *(const f32x4*)(p0 + st);
    f32x4 c = *(const f32x4*)(p0 + 2 * st);
    f32x4 d = *(const f32x4*)(p0 + 3 * st);
    float inv = 1.0f / (lpart[row] + lpart[NROWS + row] +
                        lpart[2 * NROWS + row] + lpart[3 * NROWS + row]);
    f32x4 res = (a + b) + (c + d);
    res[0] *= inv; res[1] *= inv; res[2] *= inv; res[3] *= inv;
    *(f32x4*)(out + (size_t)row * HEAD + d4) = res;
}

extern "C" void kernel_launch(void* const* d_in, const int* in_sizes, int n_in,
                              void* d_out, int out_size, void* d_ws, size_t ws_size,
                              hipStream_t stream)
{
    const float* x  = (const float*)d_in[0];
    const float* Wq = (const float*)d_in[1];
    const float* Wk = (const float*)d_in[2];
    const float* Wv = (const float*)d_in[3];
    float* out = (float*)d_out;

    // ws: Q | K | V^T (bf16, 2MB each) | W^T (144KB) | opart (16MB) | lpart (256KB)
    unsigned short* Qw  = (unsigned short*)d_ws;
    unsigned short* Kw  = Qw + (size_t)NROWS * HEAD;
    unsigned short* Vtw = Kw + (size_t)NROWS * HEAD;
    unsigned short* Wtw = Vtw + (size_t)NROWS * HEAD;
    float* opart = (float*)(Wtw + (size_t)192 * EMBED);
    float* lpart = opart + (size_t)NSPLIT * NROWS * HEAD;

    wprep_kernel<<<(192 * EMBED) / 256, 256, 0, stream>>>(Wq, Wk, Wv, Wtw);
    proj_kernel<<<256, 512, 0, stream>>>(x, Wtw, Qw, Kw, Vtw);
    attn_kernel<<<1024, 512, 0, stream>>>(Qw, Kw, Vtw, opart, lpart);
    combine_kernel<<<NROWS * 16 / 256, 256, 0, stream>>>(opart, lpart, out);
}